// Round 1
// baseline (1531.661 us; speedup 1.0000x reference)
//
#include <hip/hip_runtime.h>
#include <hip/hip_bf16.h>

#define HID 2048
#define NH 20
#define QR 768
#define KVR 512
#define DN 192
#define DR 64
#define DV 256
#define HD 256          // HEAD_DIM = DN + DR
#define S_LEN 2048
#define HKV 448         // DN + DV
#define KV_N (NH * HKV) // 8960
#define Q_N (NH * HD)   // 5120
#define O_N (NH * DV)   // 5120
#define KVA_N (KVR + DR) // 576
#define ATT_SCALE 0.0625f // 1/sqrt(256)

typedef short bf16x8 __attribute__((ext_vector_type(8)));
typedef float f32x4 __attribute__((ext_vector_type(4)));

__device__ inline short f2bs(float f) {
  __hip_bfloat16 h = __float2bfloat16(f);
  return *reinterpret_cast<short*>(&h);
}
__device__ inline float bs2f(short s) {
  __hip_bfloat16 h = *reinterpret_cast<__hip_bfloat16*>(&s);
  return __bfloat162float(h);
}

// ---------------- fp32 -> bf16 convert ----------------
__global__ void f2b_kernel(const float* __restrict__ in, short* __restrict__ out, size_t n) {
  size_t i = (size_t)blockIdx.x * blockDim.x + threadIdx.x;
  size_t stride = (size_t)gridDim.x * blockDim.x;
  for (; i < n; i += stride) out[i] = f2bs(in[i]);
}

// ---------------- generic GEMM: C[M][N] = A[M][K](bf16) @ B[N][K]^T(bf16) ----------------
// block = 64x64 tile, 4 waves; wave w owns rows [w*16, w*16+16)
template <int OUT_BF16>
__global__ __launch_bounds__(256) void gemm_bt(const short* __restrict__ A,
                                               const short* __restrict__ B,
                                               void* __restrict__ Cp,
                                               int M, int N, int K) {
  int bn = blockIdx.x, bm = blockIdx.y;
  int tid = threadIdx.x;
  int w = tid >> 6, l = tid & 63;
  int lr = l & 15, lg = l >> 4;
  int row0 = bm * 64 + w * 16;
  int col0 = bn * 64;
  f32x4 c[4] = {};
  const short* ap = A + (size_t)(row0 + lr) * K + lg * 8;
  const short* bp = B + (size_t)(col0 + lr) * K + lg * 8;
  for (int k = 0; k < K; k += 32) {
    bf16x8 a = *(const bf16x8*)(ap + k);
#pragma unroll
    for (int nt = 0; nt < 4; ++nt) {
      bf16x8 b = *(const bf16x8*)(bp + (size_t)nt * 16 * K + k);
      c[nt] = __builtin_amdgcn_mfma_f32_16x16x32_bf16(a, b, c[nt], 0, 0, 0);
    }
  }
#pragma unroll
  for (int nt = 0; nt < 4; ++nt)
#pragma unroll
    for (int r = 0; r < 4; ++r) {
      int row = row0 + lg * 4 + r;
      int col = col0 + nt * 16 + lr;
      if (OUT_BF16)
        ((short*)Cp)[(size_t)row * N + col] = f2bs(c[nt][r]);
      else
        ((float*)Cp)[(size_t)row * N + col] = c[nt][r];
    }
}

// ---------------- rmsnorm (fp32 in, bf16 out) ----------------
__global__ __launch_bounds__(256) void rmsnorm_kernel(const float* __restrict__ in,
                                                      const float* __restrict__ w,
                                                      short* __restrict__ out,
                                                      int N, int in_stride, int out_stride) {
  int row = blockIdx.x;
  const float* x = in + (size_t)row * in_stride;
  float ss = 0.f;
  for (int i = threadIdx.x; i < N; i += 256) { float v = x[i]; ss += v * v; }
#pragma unroll
  for (int off = 32; off >= 1; off >>= 1) ss += __shfl_down(ss, off);
  __shared__ float red[4];
  if ((threadIdx.x & 63) == 0) red[threadIdx.x >> 6] = ss;
  __syncthreads();
  float tot = red[0] + red[1] + red[2] + red[3];
  float sc = rsqrtf(tot / (float)N + 1e-5f);
  short* o = out + (size_t)row * out_stride;
  for (int i = threadIdx.x; i < N; i += 256) o[i] = f2bs(x[i] * sc * w[i]);
}

// ---------------- rope tables (double precision trig) ----------------
__global__ void rope_table_kernel(const int* __restrict__ pos, float* __restrict__ ct,
                                  float* __restrict__ st) {
  int s = blockIdx.x * blockDim.x + threadIdx.x;
  if (s >= S_LEN) return;
  double p = (double)pos[s];
  for (int d = 0; d < 32; ++d) {
    double invf = exp(-((double)(2 * d) / 64.0) * log(1.0e6));
    double a = p * invf;
    ct[s * 32 + d] = (float)cos(a);
    st[s * 32 + d] = (float)sin(a);
  }
}

// ---------------- rope applied in-place to q's rope slice ----------------
__global__ void rope_q_kernel(short* __restrict__ q, const float* __restrict__ ct,
                              const float* __restrict__ st) {
  int idx = blockIdx.x * blockDim.x + threadIdx.x;
  if (idx >= S_LEN * NH) return;
  int s = idx / NH, h = idx % NH;
  short* p = q + (size_t)s * Q_N + h * HD + DN;
  float x[64];
#pragma unroll
  for (int i = 0; i < 64; ++i) x[i] = bs2f(p[i]);
  const float* c = ct + s * 32;
  const float* sn = st + s * 32;
#pragma unroll
  for (int d = 0; d < 32; ++d) {
    float x1 = x[2 * d], x2 = x[2 * d + 1];
    p[d] = f2bs(x1 * c[d] - x2 * sn[d]);
    p[32 + d] = f2bs(x1 * sn[d] + x2 * c[d]);
  }
}

// ---------------- rope for shared k_rope (fp32 kv_c slice -> bf16 kr) ----------------
__global__ void rope_k_kernel(const float* __restrict__ kv_c, const float* __restrict__ ct,
                              const float* __restrict__ st, short* __restrict__ kr) {
  int s = blockIdx.x * blockDim.x + threadIdx.x;
  if (s >= S_LEN) return;
  const float* x = kv_c + (size_t)s * KVA_N + KVR;
  const float* c = ct + s * 32;
  const float* sn = st + s * 32;
  short* o = kr + s * 64;
#pragma unroll
  for (int d = 0; d < 32; ++d) {
    float x1 = x[2 * d], x2 = x[2 * d + 1];
    o[d] = f2bs(x1 * c[d] - x2 * sn[d]);
    o[32 + d] = f2bs(x1 * sn[d] + x2 * c[d]);
  }
}

// ---------------- fused flash attention ----------------
// grid = (S/64, NH); block = 256 (4 waves x 16 q-rows); KV-block = 32 keys
__global__ __launch_bounds__(256) void attn_kernel(const short* __restrict__ q,
                                                   const short* __restrict__ kvx,
                                                   const short* __restrict__ kr,
                                                   short* __restrict__ out) {
  int h = blockIdx.y;
  int qblk = blockIdx.x;
  int tid = threadIdx.x;
  int w = tid >> 6, l = tid & 63;
  int lr = l & 15, lg = l >> 4;

  __shared__ alignas(16) short vt[256 * 40];      // V^T staged: vt[d][key], stride 40
  __shared__ alignas(16) short pb[4][16][32];     // per-wave P tile

  int qrow = qblk * 64 + w * 16 + lr;
  const short* qbase = q + (size_t)qrow * Q_N + h * HD;
  bf16x8 qf[8];
#pragma unroll
  for (int kk = 0; kk < 8; ++kk) qf[kk] = *(const bf16x8*)(qbase + kk * 32 + lg * 8);

  f32x4 acc[16] = {};
  float m[4] = {-1e30f, -1e30f, -1e30f, -1e30f};
  float lsum[4] = {0.f, 0.f, 0.f, 0.f};

  for (int kb = 0; kb < S_LEN / 32; ++kb) {
    int key0 = kb * 32;
    __syncthreads();  // previous iteration's vt reads done
    {
      // stage V^T: 32 keys x 256 dims; thread t: key-pair (tid&15), d-block (tid>>4)
      int kp = tid & 15, db = tid >> 4;
      const short* v0 = kvx + (size_t)(key0 + 2 * kp) * KV_N + h * HKV + DN + db * 16;
      bf16x8 r0a = *(const bf16x8*)v0;
      bf16x8 r0b = *(const bf16x8*)(v0 + 8);
      bf16x8 r1a = *(const bf16x8*)(v0 + KV_N);
      bf16x8 r1b = *(const bf16x8*)(v0 + KV_N + 8);
#pragma unroll
      for (int j = 0; j < 8; ++j) {
        short2 t0; t0.x = r0a[j]; t0.y = r1a[j];
        *(short2*)&vt[(db * 16 + j) * 40 + 2 * kp] = t0;
        short2 t1; t1.x = r0b[j]; t1.y = r1b[j];
        *(short2*)&vt[(db * 16 + 8 + j) * 40 + 2 * kp] = t1;
      }
    }
    __syncthreads();

    // QK^T for 16 q-rows x 32 keys
    f32x4 s0 = {}, s1 = {};
#pragma unroll
    for (int kk = 0; kk < 8; ++kk) {
      int d = kk * 32 + lg * 8;
      const short *p0, *p1;
      if (kk < 6) {  // d < 192: k_nope from kv_exp
        p0 = kvx + (size_t)(key0 + lr) * KV_N + h * HKV + d;
        p1 = p0 + (size_t)16 * KV_N;
      } else {       // d >= 192: roped shared k_rope
        p0 = kr + (size_t)(key0 + lr) * 64 + (d - DN);
        p1 = p0 + 16 * 64;
      }
      bf16x8 k0 = *(const bf16x8*)p0;
      bf16x8 k1 = *(const bf16x8*)p1;
      s0 = __builtin_amdgcn_mfma_f32_16x16x32_bf16(qf[kk], k0, s0, 0, 0, 0);
      s1 = __builtin_amdgcn_mfma_f32_16x16x32_bf16(qf[kk], k1, s1, 0, 0, 0);
    }

    // online softmax (rows live on 16-lane groups: row = lg*4+r, col = lr)
    float corr[4];
#pragma unroll
    for (int r = 0; r < 4; ++r) {
      float a0 = s0[r] * ATT_SCALE, a1 = s1[r] * ATT_SCALE;
      float mx = fmaxf(a0, a1);
#pragma unroll
      for (int off = 1; off < 16; off <<= 1) mx = fmaxf(mx, __shfl_xor(mx, off));
      float mn = fmaxf(m[r], mx);
      float co = __expf(m[r] - mn);
      float p0v = __expf(a0 - mn), p1v = __expf(a1 - mn);
      float rs = p0v + p1v;
#pragma unroll
      for (int off = 1; off < 16; off <<= 1) rs += __shfl_xor(rs, off);
      lsum[r] = lsum[r] * co + rs;
      m[r] = mn;
      corr[r] = co;
      pb[w][lg * 4 + r][lr] = f2bs(p0v);
      pb[w][lg * 4 + r][16 + lr] = f2bs(p1v);
    }
#pragma unroll
    for (int t = 0; t < 16; ++t)
#pragma unroll
      for (int r = 0; r < 4; ++r) acc[t][r] *= corr[r];

    asm volatile("s_waitcnt lgkmcnt(0)" ::: "memory");

    // PV: acc[16 rows][256] += P[16][32] @ V[32][256]
    bf16x8 pf = *(const bf16x8*)&pb[w][lr][lg * 8];
#pragma unroll
    for (int t = 0; t < 16; ++t) {
      bf16x8 vf = *(const bf16x8*)&vt[(t * 16 + lr) * 40 + lg * 8];
      acc[t] = __builtin_amdgcn_mfma_f32_16x16x32_bf16(pf, vf, acc[t], 0, 0, 0);
    }
  }

#pragma unroll
  for (int t = 0; t < 16; ++t)
#pragma unroll
    for (int r = 0; r < 4; ++r) {
      int row = qblk * 64 + w * 16 + lg * 4 + r;
      int col = h * DV + t * 16 + lr;
      out[(size_t)row * O_N + col] = f2bs(acc[t][r] / lsum[r]);
    }
}

extern "C" void kernel_launch(void* const* d_in, const int* in_sizes, int n_in,
                              void* d_out, int out_size, void* d_ws, size_t ws_size,
                              hipStream_t stream) {
  const float* x       = (const float*)d_in[0];
  const int*   pos     = (const int*)d_in[1];
  const float* q_a_w   = (const float*)d_in[2];
  const float* q_b_w   = (const float*)d_in[3];
  const float* kv_a_w  = (const float*)d_in[4];
  const float* kv_b_w  = (const float*)d_in[5];
  const float* o_w     = (const float*)d_in[6];
  const float* q_a_ln  = (const float*)d_in[7];
  const float* kv_a_ln = (const float*)d_in[8];
  float* out = (float*)d_out;

  char* p = (char*)d_ws;
  auto alloc = [&](size_t bytes) {
    char* r = p;
    p += (bytes + 255) & ~(size_t)255;
    return r;
  };
  short* xb    = (short*)alloc((size_t)S_LEN * HID * 2);
  short* qaw   = (short*)alloc((size_t)QR * HID * 2);
  short* qbw   = (short*)alloc((size_t)Q_N * QR * 2);
  short* kvaw  = (short*)alloc((size_t)KVA_N * HID * 2);
  short* kvbw  = (short*)alloc((size_t)KV_N * KVR * 2);
  short* ow    = (short*)alloc((size_t)HID * O_N * 2);
  float* q_a   = (float*)alloc((size_t)S_LEN * QR * 4);
  short* q_ln  = (short*)alloc((size_t)S_LEN * QR * 2);
  short* qbuf  = (short*)alloc((size_t)S_LEN * Q_N * 2);
  float* kv_c  = (float*)alloc((size_t)S_LEN * KVA_N * 4);
  short* kv_ln = (short*)alloc((size_t)S_LEN * KVR * 2);
  short* kvx   = (short*)alloc((size_t)S_LEN * KV_N * 2);
  short* kr    = (short*)alloc((size_t)S_LEN * 64 * 2);
  float* ct    = (float*)alloc((size_t)S_LEN * 32 * 4);
  float* st    = (float*)alloc((size_t)S_LEN * 32 * 4);
  short* ao    = (short*)alloc((size_t)S_LEN * O_N * 2);
  (void)ws_size; (void)n_in; (void)in_sizes; (void)out_size;

  auto cvt = [&](const float* in, short* o, size_t n) {
    size_t blocks = (n + 255) / 256;
    if (blocks > 2048) blocks = 2048;
    f2b_kernel<<<dim3((unsigned)blocks), dim3(256), 0, stream>>>(in, o, n);
  };
  cvt(x, xb, (size_t)S_LEN * HID);
  cvt(q_a_w, qaw, (size_t)QR * HID);
  cvt(q_b_w, qbw, (size_t)Q_N * QR);
  cvt(kv_a_w, kvaw, (size_t)KVA_N * HID);
  cvt(kv_b_w, kvbw, (size_t)KV_N * KVR);
  cvt(o_w, ow, (size_t)HID * O_N);

  dim3 blk(256);
  // q_a = x @ q_a_w^T ; kv_c = x @ kv_a_w^T  (fp32 out)
  gemm_bt<0><<<dim3(QR / 64, S_LEN / 64), blk, 0, stream>>>(xb, qaw, q_a, S_LEN, QR, HID);
  gemm_bt<0><<<dim3(KVA_N / 64, S_LEN / 64), blk, 0, stream>>>(xb, kvaw, kv_c, S_LEN, KVA_N, HID);
  // rmsnorms -> bf16
  rmsnorm_kernel<<<dim3(S_LEN), blk, 0, stream>>>(q_a, q_a_ln, q_ln, QR, QR, QR);
  rmsnorm_kernel<<<dim3(S_LEN), blk, 0, stream>>>(kv_c, kv_a_ln, kv_ln, KVR, KVA_N, KVR);
  // up-projections -> bf16
  gemm_bt<1><<<dim3(Q_N / 64, S_LEN / 64), blk, 0, stream>>>(q_ln, qbw, qbuf, S_LEN, Q_N, QR);
  gemm_bt<1><<<dim3(KV_N / 64, S_LEN / 64), blk, 0, stream>>>(kv_ln, kvbw, kvx, S_LEN, KV_N, KVR);
  // rope
  rope_table_kernel<<<dim3(S_LEN / 256), blk, 0, stream>>>(pos, ct, st);
  rope_q_kernel<<<dim3((S_LEN * NH + 255) / 256), blk, 0, stream>>>(qbuf, ct, st);
  rope_k_kernel<<<dim3(S_LEN / 256), blk, 0, stream>>>(kv_c, ct, st, kr);
  // fused attention
  attn_kernel<<<dim3(S_LEN / 64, NH), blk, 0, stream>>>(qbuf, kvx, kr, ao);
  // output projection (fp32 out)
  gemm_bt<0><<<dim3(HID / 64, S_LEN / 64), blk, 0, stream>>>(ao, ow, out, S_LEN, HID, O_N);
}

// Round 2
// 637.836 us; speedup vs baseline: 2.4013x; 2.4013x over previous
//
#include <hip/hip_runtime.h>
#include <hip/hip_bf16.h>

#define HID 2048
#define NH 20
#define QR 768
#define KVR 512
#define DN 192
#define DR 64
#define DV 256
#define HD 256          // HEAD_DIM = DN + DR
#define S_LEN 2048
#define HKV 448         // DN + DV
#define KV_N (NH * HKV) // 8960
#define Q_N (NH * HD)   // 5120
#define O_N (NH * DV)   // 5120
#define KVA_N (KVR + DR) // 576
#define ATT_SCALE 0.0625f // 1/sqrt(256)

typedef short bf16x8 __attribute__((ext_vector_type(8)));
typedef float f32x4 __attribute__((ext_vector_type(4)));

__device__ inline short f2bs(float f) {
  __hip_bfloat16 h = __float2bfloat16(f);
  return *reinterpret_cast<short*>(&h);
}
__device__ inline float bs2f(short s) {
  __hip_bfloat16 h = *reinterpret_cast<__hip_bfloat16*>(&s);
  return __bfloat162float(h);
}

// async global->LDS, 16B per lane. LDS dest must be linear in lane order.
__device__ inline void gload16(const void* g, void* l) {
  __builtin_amdgcn_global_load_lds((const __attribute__((address_space(1))) void*)g,
                                   (__attribute__((address_space(3))) void*)l, 16, 0, 0);
}

// ---------------- fp32 -> bf16 convert ----------------
__global__ void f2b_kernel(const float* __restrict__ in, short* __restrict__ out, size_t n) {
  size_t i = (size_t)blockIdx.x * blockDim.x + threadIdx.x;
  size_t stride = (size_t)gridDim.x * blockDim.x;
  for (; i < n; i += stride) out[i] = f2bs(in[i]);
}

// ---------------- small GEMM (64x64 tile): C = A @ B^T ----------------
template <int OUT_BF16>
__global__ __launch_bounds__(256) void gemm_bt(const short* __restrict__ A,
                                               const short* __restrict__ B,
                                               void* __restrict__ Cp,
                                               int M, int N, int K) {
  int bn = blockIdx.x, bm = blockIdx.y;
  int tid = threadIdx.x;
  int w = tid >> 6, l = tid & 63;
  int lr = l & 15, lg = l >> 4;
  int row0 = bm * 64 + w * 16;
  int col0 = bn * 64;
  f32x4 c[4] = {};
  const short* ap = A + (size_t)(row0 + lr) * K + lg * 8;
  const short* bp = B + (size_t)(col0 + lr) * K + lg * 8;
  for (int k = 0; k < K; k += 32) {
    bf16x8 a = *(const bf16x8*)(ap + k);
#pragma unroll
    for (int nt = 0; nt < 4; ++nt) {
      bf16x8 b = *(const bf16x8*)(bp + (size_t)nt * 16 * K + k);
      c[nt] = __builtin_amdgcn_mfma_f32_16x16x32_bf16(a, b, c[nt], 0, 0, 0);
    }
  }
#pragma unroll
  for (int nt = 0; nt < 4; ++nt)
#pragma unroll
    for (int r = 0; r < 4; ++r) {
      int row = row0 + lg * 4 + r;
      int col = col0 + nt * 16 + lr;
      if (OUT_BF16)
        ((short*)Cp)[(size_t)row * N + col] = f2bs(c[nt][r]);
      else
        ((float*)Cp)[(size_t)row * N + col] = c[nt][r];
    }
}

// ---------------- big GEMM: 128x128 tile, BK=64, global_load_lds + XOR swizzle ----------------
// C[M][N] = A[M][K] @ B[N][K]^T, all dims: M%128==0, N%128==0, K%64==0
template <int OUT_BF16>
__global__ __launch_bounds__(256) void gemm128(const short* __restrict__ A,
                                               const short* __restrict__ B,
                                               void* __restrict__ Cp,
                                               int M, int N, int K) {
  __shared__ alignas(16) short As[128 * 64];
  __shared__ alignas(16) short Bs[128 * 64];
  int tid = threadIdx.x;
  int w = tid >> 6, l = tid & 63;
  int lr = l & 15, lg = l >> 4;
  int wr = w >> 1, wc = w & 1;
  int row0 = blockIdx.y * 128, col0 = blockIdx.x * 128;
  f32x4 acc[4][4] = {};
  for (int k0 = 0; k0 < K; k0 += 64) {
    if (k0) __syncthreads();
    // stage 128x64 bf16 tiles (16KB each). LDS linear; source pre-swizzled so
    // that LDS[row*128 + b] = G[row*128 + (b ^ ((row&7)<<4))].
#pragma unroll
    for (int p = 0; p < 4; ++p) {
      int c = p * 256 + tid;      // 16B chunk id, 1024 total
      int row = c >> 3;           // 8 chunks per 128B row
      int bofs = (c & 7) * 16;
      int sb = bofs ^ ((row & 7) << 4);
      gload16((const char*)A + ((size_t)(row0 + row) * K + k0) * 2 + sb, (char*)As + c * 16);
      gload16((const char*)B + ((size_t)(col0 + row) * K + k0) * 2 + sb, (char*)Bs + c * 16);
    }
    __syncthreads();
    bf16x8 af[4][2], bf[4][2];
#pragma unroll
    for (int m = 0; m < 4; ++m)
#pragma unroll
      for (int kk = 0; kk < 2; ++kk) {
        int ra = wr * 64 + m * 16 + lr;
        int rb = wc * 64 + m * 16 + lr;
        int cb = kk * 64 + lg * 16;
        af[m][kk] = *(const bf16x8*)((const char*)As + ra * 128 + (cb ^ ((ra & 7) << 4)));
        bf[m][kk] = *(const bf16x8*)((const char*)Bs + rb * 128 + (cb ^ ((rb & 7) << 4)));
      }
#pragma unroll
    for (int m = 0; m < 4; ++m)
#pragma unroll
      for (int n = 0; n < 4; ++n) {
        acc[m][n] = __builtin_amdgcn_mfma_f32_16x16x32_bf16(af[m][0], bf[n][0], acc[m][n], 0, 0, 0);
        acc[m][n] = __builtin_amdgcn_mfma_f32_16x16x32_bf16(af[m][1], bf[n][1], acc[m][n], 0, 0, 0);
      }
  }
#pragma unroll
  for (int m = 0; m < 4; ++m)
#pragma unroll
    for (int n = 0; n < 4; ++n)
#pragma unroll
      for (int r = 0; r < 4; ++r) {
        int row = row0 + wr * 64 + m * 16 + lg * 4 + r;
        int col = col0 + wc * 64 + n * 16 + lr;
        if (OUT_BF16)
          ((short*)Cp)[(size_t)row * N + col] = f2bs(acc[m][n][r]);
        else
          ((float*)Cp)[(size_t)row * N + col] = acc[m][n][r];
      }
}

// ---------------- rmsnorm (fp32 in, bf16 out) ----------------
__global__ __launch_bounds__(256) void rmsnorm_kernel(const float* __restrict__ in,
                                                      const float* __restrict__ w,
                                                      short* __restrict__ out,
                                                      int N, int in_stride, int out_stride) {
  int row = blockIdx.x;
  const float* x = in + (size_t)row * in_stride;
  float ss = 0.f;
  for (int i = threadIdx.x; i < N; i += 256) { float v = x[i]; ss += v * v; }
#pragma unroll
  for (int off = 32; off >= 1; off >>= 1) ss += __shfl_down(ss, off);
  __shared__ float red[4];
  if ((threadIdx.x & 63) == 0) red[threadIdx.x >> 6] = ss;
  __syncthreads();
  float tot = red[0] + red[1] + red[2] + red[3];
  float sc = rsqrtf(tot / (float)N + 1e-5f);
  short* o = out + (size_t)row * out_stride;
  for (int i = threadIdx.x; i < N; i += 256) o[i] = f2bs(x[i] * sc * w[i]);
}

// ---------------- rope tables ----------------
__global__ void rope_table_kernel(const int* __restrict__ pos, float* __restrict__ ct,
                                  float* __restrict__ st) {
  int s = blockIdx.x * blockDim.x + threadIdx.x;
  if (s >= S_LEN) return;
  double p = (double)pos[s];
  for (int d = 0; d < 32; ++d) {
    double invf = exp(-((double)(2 * d) / 64.0) * log(1.0e6));
    double a = p * invf;
    ct[s * 32 + d] = (float)cos(a);
    st[s * 32 + d] = (float)sin(a);
  }
}

// ---------------- rope applied in-place to q's rope slice ----------------
__global__ void rope_q_kernel(short* __restrict__ q, const float* __restrict__ ct,
                              const float* __restrict__ st) {
  int idx = blockIdx.x * blockDim.x + threadIdx.x;
  if (idx >= S_LEN * NH) return;
  int s = idx / NH, h = idx % NH;
  short* p = q + (size_t)s * Q_N + h * HD + DN;
  float x[64];
#pragma unroll
  for (int i = 0; i < 64; ++i) x[i] = bs2f(p[i]);
  const float* c = ct + s * 32;
  const float* sn = st + s * 32;
#pragma unroll
  for (int d = 0; d < 32; ++d) {
    float x1 = x[2 * d], x2 = x[2 * d + 1];
    p[d] = f2bs(x1 * c[d] - x2 * sn[d]);
    p[32 + d] = f2bs(x1 * sn[d] + x2 * c[d]);
  }
}

// ---------------- rope for shared k_rope ----------------
__global__ void rope_k_kernel(const float* __restrict__ kv_c, const float* __restrict__ ct,
                              const float* __restrict__ st, short* __restrict__ kr) {
  int s = blockIdx.x * blockDim.x + threadIdx.x;
  if (s >= S_LEN) return;
  const float* x = kv_c + (size_t)s * KVA_N + KVR;
  const float* c = ct + s * 32;
  const float* sn = st + s * 32;
  short* o = kr + s * 64;
#pragma unroll
  for (int d = 0; d < 32; ++d) {
    float x1 = x[2 * d], x2 = x[2 * d + 1];
    o[d] = f2bs(x1 * c[d] - x2 * sn[d]);
    o[32 + d] = f2bs(x1 * sn[d] + x2 * c[d]);
  }
}

// ---------------- build Kc[h][s][256] = k_nope ‖ roped k_rope ----------------
__global__ void kc_build(const short* __restrict__ kvx, const short* __restrict__ kr,
                         short* __restrict__ kc) {
  int idx = blockIdx.x * 256 + threadIdx.x;  // NH*S*32 chunks of 8 elems
  int h = idx >> 16;                          // S*32 = 65536
  int r = idx & 65535;
  int s = r >> 5, c = r & 31;
  const short* src = (c < 24) ? kvx + (size_t)s * KV_N + h * HKV + c * 8
                              : kr + (size_t)s * 64 + (c - 24) * 8;
  *(bf16x8*)(kc + ((size_t)h * S_LEN + s) * HD + c * 8) = *(const bf16x8*)src;
}

// ---------------- transpose V: Vt[h][d][s] from kvx[s][h*448+192+d] ----------------
__global__ __launch_bounds__(256) void vtrans(const short* __restrict__ kvx,
                                              short* __restrict__ vtg) {
  __shared__ short tile[64][65];
  int s0 = blockIdx.x * 64, d0 = blockIdx.y * 64, h = blockIdx.z;
  int tid = threadIdx.x;
#pragma unroll
  for (int p = 0; p < 2; ++p) {
    int s = p * 32 + (tid >> 3), dc = (tid & 7) * 8;
    bf16x8 v = *(const bf16x8*)(kvx + (size_t)(s0 + s) * KV_N + h * HKV + DN + d0 + dc);
#pragma unroll
    for (int j = 0; j < 8; ++j) tile[s][dc + j] = v[j];
  }
  __syncthreads();
#pragma unroll
  for (int p = 0; p < 2; ++p) {
    int d = p * 32 + (tid >> 3), sc = (tid & 7) * 8;
    bf16x8 o;
#pragma unroll
    for (int j = 0; j < 8; ++j) o[j] = tile[sc + j][d];
    *(bf16x8*)(vtg + ((size_t)h * DV + d0 + d) * S_LEN + s0 + sc) = o;
  }
}

// ---------------- fused flash attention v2 ----------------
// grid = (S/64, NH); 256 thr (4 waves x 16 q-rows); KV-block = 32 keys
// Kc staged via global_load_lds w/ swizzled source; Vt reg-staged into padded LDS.
__global__ __launch_bounds__(256) void attn2(const short* __restrict__ q,
                                             const short* __restrict__ kc,
                                             const short* __restrict__ vtg,
                                             short* __restrict__ out) {
  __shared__ alignas(16) short ks[32 * 256];    // 16KB, 512B rows, src-swizzled
  __shared__ alignas(16) short vt[256 * 40];    // 20KB, vt[d][key], stride 40
  __shared__ alignas(16) short pb[4][16][32];   // per-wave P tile
  int h = blockIdx.y, qblk = blockIdx.x;
  int tid = threadIdx.x;
  int w = tid >> 6, l = tid & 63;
  int lr = l & 15, lg = l >> 4;

  int qrow = qblk * 64 + w * 16 + lr;
  const short* qbase = q + (size_t)qrow * Q_N + h * HD;
  bf16x8 qf[8];
#pragma unroll
  for (int kk = 0; kk < 8; ++kk) qf[kk] = *(const bf16x8*)(qbase + kk * 32 + lg * 8);

  const char* kch = (const char*)(kc + (size_t)h * S_LEN * HD);
  const short* vth = vtg + (size_t)h * DV * S_LEN;

  f32x4 acc[16] = {};
  float m[4] = {-1e30f, -1e30f, -1e30f, -1e30f};
  float lsum[4] = {0.f, 0.f, 0.f, 0.f};

  for (int kb = 0; kb < S_LEN / 32; ++kb) {
    int key0 = kb * 32;
    __syncthreads();  // previous iteration's LDS reads done
    // stage K tile [32][256] (16KB): LDS[row*512+b] = Kc[row*512 + (b^((row&7)<<4))]
#pragma unroll
    for (int p = 0; p < 4; ++p) {
      int c = p * 256 + tid;
      int row = c >> 5;            // 32 chunks per 512B row
      int bofs = (c & 31) * 16;
      int sb = bofs ^ ((row & 7) << 4);
      gload16(kch + (size_t)(key0 + row) * 512 + sb, (char*)ks + c * 16);
    }
    // stage Vt tile [256][32] into padded [256][40]
    bf16x8 vreg[4];
#pragma unroll
    for (int p = 0; p < 4; ++p) {
      int c = p * 256 + tid;
      int vr = c >> 2, so = c & 3;
      vreg[p] = *(const bf16x8*)(vth + (size_t)vr * S_LEN + key0 + so * 8);
    }
#pragma unroll
    for (int p = 0; p < 4; ++p) {
      int c = p * 256 + tid;
      int vr = c >> 2, so = c & 3;
      *(bf16x8*)&vt[vr * 40 + so * 8] = vreg[p];
    }
    __syncthreads();

    // QK^T: 16 q-rows x 32 keys per wave
    f32x4 s0 = {}, s1 = {};
#pragma unroll
    for (int kk = 0; kk < 8; ++kk) {
      int cb = kk * 64 + lg * 16;
      int r0 = lr, r1 = 16 + lr;
      bf16x8 k0 = *(const bf16x8*)((const char*)ks + r0 * 512 + (cb ^ ((r0 & 7) << 4)));
      bf16x8 k1 = *(const bf16x8*)((const char*)ks + r1 * 512 + (cb ^ ((r1 & 7) << 4)));
      s0 = __builtin_amdgcn_mfma_f32_16x16x32_bf16(qf[kk], k0, s0, 0, 0, 0);
      s1 = __builtin_amdgcn_mfma_f32_16x16x32_bf16(qf[kk], k1, s1, 0, 0, 0);
    }

    // online softmax (row = lg*4+r on 16-lane groups, col = lr)
    float corr[4];
#pragma unroll
    for (int r = 0; r < 4; ++r) {
      float a0 = s0[r] * ATT_SCALE, a1 = s1[r] * ATT_SCALE;
      float mx = fmaxf(a0, a1);
#pragma unroll
      for (int off = 1; off < 16; off <<= 1) mx = fmaxf(mx, __shfl_xor(mx, off));
      float mn = fmaxf(m[r], mx);
      float co = __expf(m[r] - mn);
      float p0v = __expf(a0 - mn), p1v = __expf(a1 - mn);
      float rs = p0v + p1v;
#pragma unroll
      for (int off = 1; off < 16; off <<= 1) rs += __shfl_xor(rs, off);
      lsum[r] = lsum[r] * co + rs;
      m[r] = mn;
      corr[r] = co;
      pb[w][lg * 4 + r][lr] = f2bs(p0v);
      pb[w][lg * 4 + r][16 + lr] = f2bs(p1v);
    }
#pragma unroll
    for (int t = 0; t < 16; ++t)
#pragma unroll
      for (int r = 0; r < 4; ++r) acc[t][r] *= corr[r];

    asm volatile("s_waitcnt lgkmcnt(0)" ::: "memory");

    // PV: acc[16 rows][256] += P[16][32] @ V[32][256]
    bf16x8 pf = *(const bf16x8*)&pb[w][lr][lg * 8];
#pragma unroll
    for (int t = 0; t < 16; ++t) {
      bf16x8 vf = *(const bf16x8*)&vt[(t * 16 + lr) * 40 + lg * 8];
      acc[t] = __builtin_amdgcn_mfma_f32_16x16x32_bf16(pf, vf, acc[t], 0, 0, 0);
    }
  }

#pragma unroll
  for (int t = 0; t < 16; ++t)
#pragma unroll
    for (int r = 0; r < 4; ++r) {
      int row = qblk * 64 + w * 16 + lg * 4 + r;
      int col = h * DV + t * 16 + lr;
      out[(size_t)row * O_N + col] = f2bs(acc[t][r] / lsum[r]);
    }
}

extern "C" void kernel_launch(void* const* d_in, const int* in_sizes, int n_in,
                              void* d_out, int out_size, void* d_ws, size_t ws_size,
                              hipStream_t stream) {
  const float* x       = (const float*)d_in[0];
  const int*   pos     = (const int*)d_in[1];
  const float* q_a_w   = (const float*)d_in[2];
  const float* q_b_w   = (const float*)d_in[3];
  const float* kv_a_w  = (const float*)d_in[4];
  const float* kv_b_w  = (const float*)d_in[5];
  const float* o_w     = (const float*)d_in[6];
  const float* q_a_ln  = (const float*)d_in[7];
  const float* kv_a_ln = (const float*)d_in[8];
  float* out = (float*)d_out;

  char* p = (char*)d_ws;
  auto alloc = [&](size_t bytes) {
    char* r = p;
    p += (bytes + 255) & ~(size_t)255;
    return r;
  };
  short* xb    = (short*)alloc((size_t)S_LEN * HID * 2);
  short* qaw   = (short*)alloc((size_t)QR * HID * 2);
  short* qbw   = (short*)alloc((size_t)Q_N * QR * 2);
  short* kvaw  = (short*)alloc((size_t)KVA_N * HID * 2);
  short* kvbw  = (short*)alloc((size_t)KV_N * KVR * 2);
  short* ow    = (short*)alloc((size_t)HID * O_N * 2);
  float* q_a   = (float*)alloc((size_t)S_LEN * QR * 4);
  short* q_ln  = (short*)alloc((size_t)S_LEN * QR * 2);
  short* qbuf  = (short*)alloc((size_t)S_LEN * Q_N * 2);
  float* kv_c  = (float*)alloc((size_t)S_LEN * KVA_N * 4);
  short* kv_ln = (short*)alloc((size_t)S_LEN * KVR * 2);
  short* kvx   = (short*)alloc((size_t)S_LEN * KV_N * 2);
  short* kr    = (short*)alloc((size_t)S_LEN * 64 * 2);
  float* ct    = (float*)alloc((size_t)S_LEN * 32 * 4);
  float* st    = (float*)alloc((size_t)S_LEN * 32 * 4);
  short* ao    = (short*)alloc((size_t)S_LEN * O_N * 2);
  short* kcb   = (short*)alloc((size_t)NH * S_LEN * HD * 2);
  short* vtg   = (short*)alloc((size_t)NH * DV * S_LEN * 2);
  (void)ws_size; (void)n_in; (void)in_sizes; (void)out_size;

  auto cvt = [&](const float* in, short* o, size_t n) {
    size_t blocks = (n + 255) / 256;
    if (blocks > 2048) blocks = 2048;
    f2b_kernel<<<dim3((unsigned)blocks), dim3(256), 0, stream>>>(in, o, n);
  };
  cvt(x, xb, (size_t)S_LEN * HID);
  cvt(q_a_w, qaw, (size_t)QR * HID);
  cvt(q_b_w, qbw, (size_t)Q_N * QR);
  cvt(kv_a_w, kvaw, (size_t)KVA_N * HID);
  cvt(kv_b_w, kvbw, (size_t)KV_N * KVR);
  cvt(o_w, ow, (size_t)HID * O_N);

  dim3 blk(256);
  // q_a = x @ q_a_w^T (fp32 out); kv_c = x @ kv_a_w^T (fp32 out, N=576 -> small gemm)
  gemm128<0><<<dim3(QR / 128, S_LEN / 128), blk, 0, stream>>>(xb, qaw, q_a, S_LEN, QR, HID);
  gemm_bt<0><<<dim3(KVA_N / 64, S_LEN / 64), blk, 0, stream>>>(xb, kvaw, kv_c, S_LEN, KVA_N, HID);
  // rmsnorms -> bf16
  rmsnorm_kernel<<<dim3(S_LEN), blk, 0, stream>>>(q_a, q_a_ln, q_ln, QR, QR, QR);
  rmsnorm_kernel<<<dim3(S_LEN), blk, 0, stream>>>(kv_c, kv_a_ln, kv_ln, KVR, KVA_N, KVR);
  // up-projections -> bf16
  gemm128<1><<<dim3(Q_N / 128, S_LEN / 128), blk, 0, stream>>>(q_ln, qbw, qbuf, S_LEN, Q_N, QR);
  gemm128<1><<<dim3(KV_N / 128, S_LEN / 128), blk, 0, stream>>>(kv_ln, kvbw, kvx, S_LEN, KV_N, KVR);
  // rope
  rope_table_kernel<<<dim3(S_LEN / 256), blk, 0, stream>>>(pos, ct, st);
  rope_q_kernel<<<dim3((S_LEN * NH + 255) / 256), blk, 0, stream>>>(qbuf, ct, st);
  rope_k_kernel<<<dim3(S_LEN / 256), blk, 0, stream>>>(kv_c, ct, st, kr);
  // rearrange K and transpose V into per-head contiguous layouts
  kc_build<<<dim3(NH * S_LEN * 32 / 256), blk, 0, stream>>>(kvx, kr, kcb);
  vtrans<<<dim3(S_LEN / 64, DV / 64, NH), blk, 0, stream>>>(kvx, vtg);
  // fused attention
  attn2<<<dim3(S_LEN / 64, NH), blk, 0, stream>>>(qbuf, kcb, vtg, ao);
  // output projection (fp32 out)
  gemm128<0><<<dim3(HID / 128, S_LEN / 128), blk, 0, stream>>>(ao, ow, out, S_LEN, HID, O_N);
}